// Round 1
// baseline (136.345 us; speedup 1.0000x reference)
//
#include <hip/hip_runtime.h>

// ---------------------------------------------------------------------------
// Attention: y = softmax( (xWq^T)(xWk^T)^T / sqrt(128) ) (xWv^T)
// B=4, N=4096, H=OUT=128. fp32 I/O, bf16 MFMA compute.
//
// R7:
//  proj: was ~50us (1 block/CU, 1 wave/SIMD, 3 barrier-fenced phases, all
//  latency serially exposed). Now task-parallel: one wave per (16-token
//  tile, phase), 768 blocks x 4 waves, NO __syncthreads, W fragments read
//  directly from global (L2-resident 64KB) -- no LDS W staging.
//  flash: was latency-bound on the P LDS round-trip (524K bank-conflict
//  cycles + 2 lgkmcnt drains per iter). Now swapped QK^T (S^T = mfma(K,Q))
//  puts q on lane&15 == the A-fragment row -> exp2 + P-fragment build fully
//  in-register. The k-slot order of P's registers is absorbed by writing V
//  with the SAME permuted k-order per 64-key group (kappa mapping below);
//  MFMA contraction is invariant under consistent k-slot permutation.
//  V loads hoisted before QK; rowsum stays as ones-MFMA so the combine
//  epilogue is unchanged.
// ---------------------------------------------------------------------------

typedef __bf16 bf16;
typedef __attribute__((ext_vector_type(8))) __bf16 bf16x8;
typedef __attribute__((ext_vector_type(4))) __bf16 bf16x4;
typedef __attribute__((ext_vector_type(4))) float f32x4;

#define MFMA16(a, b, c) __builtin_amdgcn_mfma_f32_16x16x32_bf16(a, b, c, 0, 0, 0)
#define SB0() __builtin_amdgcn_sched_barrier(0)

#if __has_builtin(__builtin_amdgcn_exp2f)
#define EXP2F(x) __builtin_amdgcn_exp2f(x)
#else
#define EXP2F(x) exp2f(x)
#endif

static constexpr int BATCH = 4;
static constexpr int N = 4096;
static constexpr int D = 128;
static constexpr int ROWS = BATCH * N;  // 16384
// fold 1/sqrt(128) and log2(e) into q so softmax is raw exp2
static constexpr float QSCALE = 0.088388347648318447f * 1.4426950408889634f;

__device__ inline bf16x8 ld8_f32_bf16(const float* __restrict__ p) {
    f32x4 a = *(const f32x4*)p;
    f32x4 b = *(const f32x4*)(p + 4);
    bf16x8 r;
    r[0] = (bf16)a[0]; r[1] = (bf16)a[1]; r[2] = (bf16)a[2]; r[3] = (bf16)a[3];
    r[4] = (bf16)b[0]; r[5] = (bf16)b[1]; r[6] = (bf16)b[2]; r[7] = (bf16)b[3];
    return r;
}

// Fragment layouts (16x16x32 bf16; lane = quad*16 + l16):
//  qf/kf: (tile,row,d) -> ((tile*4 + (d>>5))*64 + ((d&31)>>3)*16 + row)*8 + (d&7)
//  vf (kappa-permuted): fragment (g64, ot, m), lane (quad, o15), elem j holds
//     V[64*g64 + kappa][ot*16 + o15] with
//     kappa = 32*m + (j<4 ? quad*4 + j : 16 + quad*4 + (j-4))
//  This matches the per-lane register order of S^T = mfma(K,Q) after exp2:
//     lane (quad,l16) holds P[q=l16][k = nt*16 + quad*4 + rg]  (nt=2m+j/4, rg=j&3)

// ---------------------------------------------------------------------------
// proj_all: grid 768 x 256. One wave per (16-token tile, phase).
// Blocks 0-255: Q, 256-511: K, 512-767: V. No __syncthreads; per-wave LDS
// scratch only for the C-transpose. W fragments come straight from global
// (64KB, L2-resident across all waves of a phase).
// ---------------------------------------------------------------------------
__global__ __launch_bounds__(256) void proj_all(const float* __restrict__ x,
                                                const float* __restrict__ Wq,
                                                const float* __restrict__ Wk,
                                                const float* __restrict__ Wv,
                                                bf16* __restrict__ qf,
                                                bf16* __restrict__ kf,
                                                bf16* __restrict__ vf) {
    __shared__ __attribute__((aligned(16))) bf16 Scr[4][2560];  // 20 KB

    const int lane = threadIdx.x & 63;
    const int w = threadIdx.x >> 6;
    const int l16 = lane & 15;
    const int quad = lane >> 4;
    const int task = blockIdx.x * 4 + w;  // 0..3071
    const int phase = task >> 10;         // 0=Q 1=K 2=V
    const int tile = task & 1023;         // global 16-token tile
    const int tok0 = tile << 4;

    // x fragments (A layout; identical lane layout serves as B too)
    bf16x8 xa[4];
#pragma unroll
    for (int ks = 0; ks < 4; ks++)
        xa[ks] = ld8_f32_bf16(x + (size_t)(tok0 + l16) * D + ks * 32 + quad * 8);

    const float* __restrict__ W = (phase == 0) ? Wq : (phase == 1) ? Wk : Wv;
    bf16* __restrict__ T = Scr[w];

    if (phase < 2) {
        // ---- Q or K: A = x, B = W fragment (W row n = output dim) ----
        bf16* __restrict__ outp = (phase == 0) ? qf : kf;
        const float scale = (phase == 0) ? QSCALE : 1.0f;
#pragma unroll
        for (int nt = 0; nt < 8; nt++) {
            f32x4 acc = {0.f, 0.f, 0.f, 0.f};
#pragma unroll
            for (int ks = 0; ks < 4; ks++) {
                bf16x8 bw = ld8_f32_bf16(W + (nt * 16 + l16) * D + ks * 32 + quad * 8);
                acc = MFMA16(xa[ks], bw, acc);
            }
            // C: row = token = quad*4+rg, col = n = nt*16+l16
#pragma unroll
            for (int rg = 0; rg < 4; rg++)
                T[(quad * 4 + rg) * 136 + nt * 16 + l16] = (bf16)(acc[rg] * scale);
        }
        // readback fragments (tok = l16), coalesced 1KB stores
#pragma unroll
        for (int ks = 0; ks < 4; ks++) {
            bf16x8 frag = *(const bf16x8*)&T[l16 * 136 + ks * 32 + quad * 8];
            *(bf16x8*)(outp + (((size_t)tile * 4 + ks) * 64 + lane) * 8) = frag;
        }
    } else {
        // ---- V: A = Wv fragment (row = o), B = x (col = token) ----
#pragma unroll
        for (int mt = 0; mt < 8; mt++) {
            f32x4 acc = {0.f, 0.f, 0.f, 0.f};
#pragma unroll
            for (int ks = 0; ks < 4; ks++) {
                bf16x8 aw = ld8_f32_bf16(W + (mt * 16 + l16) * D + ks * 32 + quad * 8);
                acc = MFMA16(aw, xa[ks], acc);
            }
            // C: row = o = mt*16+quad*4+rg, col = token = l16  ->  T[o][tok]
#pragma unroll
            for (int rg = 0; rg < 4; rg++)
                T[(mt * 16 + quad * 4 + rg) * 20 + l16] = (bf16)acc[rg];
        }
        // This 16-token tile covers kappa in [16*t4, 16*t4+16) of its 64-key
        // group: exactly the jh half (bf16x4) of mfma m for all quads.
        const int g64 = tok0 >> 6;
        const int t4 = (tok0 >> 4) & 3;
        const int m = t4 >> 1;
        const int jh = t4 & 1;
#pragma unroll
        for (int ot = 0; ot < 8; ot++) {
            bf16x4 v4 = *(const bf16x4*)&T[(ot * 16 + l16) * 20 + quad * 4];
            *(bf16x4*)(vf + ((((size_t)g64 * 8 + ot) * 2 + m) * 64 + lane) * 8 +
                       jh * 4) = v4;
        }
    }
}

// ---------------------------------------------------------------------------
// flash: grid 512 x 256 (4 waves). Block = 32 q-rows (2 tiles); wave w =
// key-split w (1024 keys, 16 iters of 64). Swapped QK^T -> P built fully
// in-register (no P LDS, no bank conflicts); V loads hoisted before QK;
// next-iter K prefetched during exp2/PV. fp32 split-combine via LDS.
// ---------------------------------------------------------------------------
__global__ __launch_bounds__(256) __attribute__((amdgpu_waves_per_eu(2, 2)))
void flash(const bf16* __restrict__ qf,
           const bf16* __restrict__ kf,
           const bf16* __restrict__ vf,
           float* __restrict__ out) {
    __shared__ __attribute__((aligned(16))) float Rs[3][2][16 * 148];  // 56832B

    const int lane = threadIdx.x & 63;
    const int w = threadIdx.x >> 6;  // 0..3 = key split
    const int l16 = lane & 15;
    const int quad = lane >> 4;

    // XCD swizzle: bid%8 = XCD; 2 XCDs per batch -> K/V (2MB) L2-resident.
    const int lo = blockIdx.x & 7;
    const int hi = blockIdx.x >> 3;
    const int batch = lo >> 1;
    const int qpair = hi * 2 + (lo & 1);       // 0..127
    const int qtg0 = batch * 256 + qpair * 2;  // global q-tile of tile 0

    bf16x8 aq[2][4];
#pragma unroll
    for (int qt = 0; qt < 2; qt++)
#pragma unroll
        for (int ks = 0; ks < 4; ks++)
            aq[qt][ks] =
                *(const bf16x8*)(qf + (((size_t)(qtg0 + qt) * 4 + ks) * 64 + lane) * 8);

    f32x4 oacc[2][9];
#pragma unroll
    for (int qt = 0; qt < 2; qt++)
#pragma unroll
        for (int i = 0; i < 9; i++) oacc[qt][i] = (f32x4){0.f, 0.f, 0.f, 0.f};

    bf16x8 vone;
#pragma unroll
    for (int j = 0; j < 8; j++) vone[j] = (bf16)1.0f;

    const int kb0 = w * (N / 4);

    // preload K batch for it=0
    bf16x8 bk[4][4];
    {
        const int ktile = batch * 256 + (kb0 >> 4);
#pragma unroll
        for (int nt = 0; nt < 4; nt++)
#pragma unroll
            for (int ks = 0; ks < 4; ks++)
                bk[nt][ks] = *(const bf16x8*)(kf +
                    (((size_t)(ktile + nt) * 4 + ks) * 64 + lane) * 8);
    }
    SB0();

#pragma unroll 1
    for (int it = 0; it < 16; it++) {
        const int kb = kb0 + it * 64;
        const size_t g64v = (size_t)batch * 64 + (kb >> 6);

        // ---- V batch 1 (ot 0..3) issued early: covered by QK + exp2 ----
        bf16x8 bv1[4][2];
#pragma unroll
        for (int ot = 0; ot < 4; ot++)
#pragma unroll
            for (int m = 0; m < 2; m++)
                bv1[ot][m] =
                    *(const bf16x8*)(vf + (((g64v * 8 + ot) * 2 + m) * 64 + lane) * 8);
        SB0();

        // ---- S^T = k.q'' (shared bk across both q-tiles) ----
        f32x4 sv[2][4];
#pragma unroll
        for (int qt = 0; qt < 2; qt++)
#pragma unroll
            for (int nt = 0; nt < 4; nt++) sv[qt][nt] = (f32x4){0.f, 0.f, 0.f, 0.f};
        __builtin_amdgcn_s_setprio(1);
#pragma unroll
        for (int ks = 0; ks < 4; ks++)
#pragma unroll
            for (int nt = 0; nt < 4; nt++) {
                sv[0][nt] = MFMA16(bk[nt][ks], aq[0][ks], sv[0][nt]);
                sv[1][nt] = MFMA16(bk[nt][ks], aq[1][ks], sv[1][nt]);
            }
        __builtin_amdgcn_s_setprio(0);
        SB0();

        // ---- V batch 2 (ot 4..7) ----
        bf16x8 bv2[4][2];
#pragma unroll
        for (int ot = 0; ot < 4; ot++)
#pragma unroll
            for (int m = 0; m < 2; m++)
                bv2[ot][m] = *(const bf16x8*)(vf +
                    (((g64v * 8 + ot + 4) * 2 + m) * 64 + lane) * 8);
        SB0();

        // ---- P = exp2(S^T) -> A-fragments, fully in-register ----
        // lane holds P[q=l16][k = nt*16+quad*4+rg]; ap[qt][m] packs
        // {sv[2m][0..3], sv[2m+1][0..3]} matching vf's kappa order.
        bf16x8 ap[2][2];
#pragma unroll
        for (int qt = 0; qt < 2; qt++)
#pragma unroll
            for (int m = 0; m < 2; m++) {
                bf16x8 t;
#pragma unroll
                for (int j = 0; j < 4; j++) {
                    t[j] = (bf16)EXP2F(sv[qt][2 * m][j]);
                    t[j + 4] = (bf16)EXP2F(sv[qt][2 * m + 1][j]);
                }
                ap[qt][m] = t;
            }
        SB0();

        // ---- prefetch next iter's K (bk dead after QK) ----
        {
            const int itn = (it < 15) ? it + 1 : 15;
            const int kbn = kb0 + itn * 64;
            const int ktn = batch * 256 + (kbn >> 4);
#pragma unroll
            for (int nt = 0; nt < 4; nt++)
#pragma unroll
                for (int ks = 0; ks < 4; ks++)
                    bk[nt][ks] = *(const bf16x8*)(kf +
                        (((size_t)(ktn + nt) * 4 + ks) * 64 + lane) * 8);
        }
        SB0();

        // ---- O += P.V  (D: row=q=quad*4+rg, col=o=l16 -> same as R6) ----
        __builtin_amdgcn_s_setprio(1);
#pragma unroll
        for (int ot = 0; ot < 4; ot++)
#pragma unroll
            for (int m = 0; m < 2; m++) {
                oacc[0][ot] = MFMA16(ap[0][m], bv1[ot][m], oacc[0][ot]);
                oacc[1][ot] = MFMA16(ap[1][m], bv1[ot][m], oacc[1][ot]);
            }
#pragma unroll
        for (int ot = 0; ot < 4; ot++)
#pragma unroll
            for (int m = 0; m < 2; m++) {
                oacc[0][ot + 4] = MFMA16(ap[0][m], bv2[ot][m], oacc[0][ot + 4]);
                oacc[1][ot + 4] = MFMA16(ap[1][m], bv2[ot][m], oacc[1][ot + 4]);
            }
#pragma unroll
        for (int qt = 0; qt < 2; qt++)
#pragma unroll
            for (int m = 0; m < 2; m++)
                oacc[qt][8] = MFMA16(ap[qt][m], vone, oacc[qt][8]);
        __builtin_amdgcn_s_setprio(0);
        SB0();
    }

    // ---- combine the 4 key-split partials through LDS (fp32) ----
    __syncthreads();
    if (w > 0) {
#pragma unroll
        for (int qt = 0; qt < 2; qt++) {
            float* __restrict__ dst = &Rs[w - 1][qt][0];
#pragma unroll
            for (int t = 0; t < 9; t++)
#pragma unroll
                for (int rg = 0; rg < 4; rg++)
                    dst[(quad * 4 + rg) * 148 + t * 16 + l16] = oacc[qt][t][rg];
        }
    }
    __syncthreads();
    if (w == 0) {
#pragma unroll
        for (int qt = 0; qt < 2; qt++) {
#pragma unroll
            for (int sIdx = 0; sIdx < 3; sIdx++) {
                const float* __restrict__ src = &Rs[sIdx][qt][0];
#pragma unroll
                for (int t = 0; t < 9; t++)
#pragma unroll
                    for (int rg = 0; rg < 4; rg++)
                        oacc[qt][t][rg] += src[(quad * 4 + rg) * 148 + t * 16 + l16];
            }
#pragma unroll
            for (int rg = 0; rg < 4; rg++) {
                const float rl = 1.0f / oacc[qt][8][rg];
                float* __restrict__ yrow =
                    out + (((size_t)(qtg0 + qt)) * 16 + quad * 4 + rg) * D;
#pragma unroll
                for (int t = 0; t < 8; t++)
                    yrow[t * 16 + l16] = oacc[qt][t][rg] * rl;
            }
        }
    }
}

// ---------------------------------------------------------------------------
extern "C" void kernel_launch(void* const* d_in, const int* in_sizes, int n_in,
                              void* d_out, int out_size, void* d_ws, size_t ws_size,
                              hipStream_t stream) {
    const float* x = (const float*)d_in[0];
    const float* Wq = (const float*)d_in[1];
    const float* Wk = (const float*)d_in[2];
    const float* Wv = (const float*)d_in[3];
    float* y = (float*)d_out;

    bf16* qf = (bf16*)d_ws;            // 4MB
    bf16* kf = qf + (size_t)ROWS * D;  // 4MB
    bf16* vf = kf + (size_t)ROWS * D;  // 4MB (kappa-permuted fragment layout)

    proj_all<<<768, 256, 0, stream>>>(x, Wq, Wk, Wv, qf, kf, vf);
    flash<<<512, 256, 0, stream>>>(qf, kf, vf, y);
}

// Round 2
// 120.214 us; speedup vs baseline: 1.1342x; 1.1342x over previous
//
#include <hip/hip_runtime.h>

// ---------------------------------------------------------------------------
// Attention: y = softmax( (xWq^T)(xWk^T)^T / sqrt(128) ) (xWv^T)
// B=4, N=4096, H=OUT=128. fp32 I/O, bf16 MFMA compute.
//
// R8:
//  proj: R7's direct-global W gathers regressed (scattered 32B reads, 16-row
//  stride, latency-bound -- the R6 comment already knew this). Restore R6's
//  coalesced W->LDS staging but fix R6's real problem (grid 256 = 1 block/CU,
//  3 barrier-fenced phases serial): one block per (phase, 64-token group),
//  grid 768, single __syncthreads, 52KB LDS -> 3 blocks/CU = 12 waves/CU so
//  staging latency hides under other blocks' MFMA.
//  flash: byte-identical to R7 (swapped QK^T, in-register P, kappa-permuted
//  V). Known remaining bound: 1.07GB L2 K/V ingest @ 2 waves/SIMD.
// ---------------------------------------------------------------------------

typedef __bf16 bf16;
typedef __attribute__((ext_vector_type(8))) __bf16 bf16x8;
typedef __attribute__((ext_vector_type(4))) __bf16 bf16x4;
typedef __attribute__((ext_vector_type(4))) float f32x4;

#define MFMA16(a, b, c) __builtin_amdgcn_mfma_f32_16x16x32_bf16(a, b, c, 0, 0, 0)
#define SB0() __builtin_amdgcn_sched_barrier(0)

#if __has_builtin(__builtin_amdgcn_exp2f)
#define EXP2F(x) __builtin_amdgcn_exp2f(x)
#else
#define EXP2F(x) exp2f(x)
#endif

static constexpr int BATCH = 4;
static constexpr int N = 4096;
static constexpr int D = 128;
static constexpr int ROWS = BATCH * N;  // 16384
// fold 1/sqrt(128) and log2(e) into q so softmax is raw exp2
static constexpr float QSCALE = 0.088388347648318447f * 1.4426950408889634f;

__device__ inline bf16x8 ld8_f32_bf16(const float* __restrict__ p) {
    f32x4 a = *(const f32x4*)p;
    f32x4 b = *(const f32x4*)(p + 4);
    bf16x8 r;
    r[0] = (bf16)a[0]; r[1] = (bf16)a[1]; r[2] = (bf16)a[2]; r[3] = (bf16)a[3];
    r[4] = (bf16)b[0]; r[5] = (bf16)b[1]; r[6] = (bf16)b[2]; r[7] = (bf16)b[3];
    return r;
}

// Fragment layouts (16x16x32 bf16; lane = quad*16 + l16):
//  qf/kf: (tile,row,d) -> ((tile*4 + (d>>5))*64 + ((d&31)>>3)*16 + row)*8 + (d&7)
//  vf (kappa-permuted): fragment (g64, ot, m), lane (quad, o15), elem j holds
//     V[64*g64 + kappa][ot*16 + o15] with
//     kappa = 32*m + (j<4 ? quad*4 + j : 16 + quad*4 + (j-4))
//  This matches the per-lane register order of S^T = mfma(K,Q) after exp2:
//     lane (quad,l16) holds P[q=l16][k = nt*16 + quad*4 + rg]  (nt=2m+j/4, rg=j&3)

// ---------------------------------------------------------------------------
// proj_all: grid 768 x 256. Block = (phase, 64-token group); 4 waves, one
// 16-token tile each. Stage W[phase] coalesced into LDS fragments (one
// __syncthreads), MFMA, transpose C through per-wave scratch, store.
// 52KB LDS -> 3 blocks/CU = 12 waves/CU.
// ---------------------------------------------------------------------------
__global__ __launch_bounds__(256) void proj_all(const float* __restrict__ x,
                                                const float* __restrict__ Wq,
                                                const float* __restrict__ Wk,
                                                const float* __restrict__ Wv,
                                                bf16* __restrict__ qf,
                                                bf16* __restrict__ kf,
                                                bf16* __restrict__ vf) {
    __shared__ __attribute__((aligned(16))) bf16 Wl[D * D];     // 32 KB
    __shared__ __attribute__((aligned(16))) bf16 Scr[4][2560];  // 20 KB

    const int lane = threadIdx.x & 63;
    const int w = threadIdx.x >> 6;
    const int l16 = lane & 15;
    const int quad = lane >> 4;
    const int phase = (int)(blockIdx.x % 3u);   // 0=Q 1=K 2=V
    const int group = (int)(blockIdx.x / 3u);   // 0..255 = 64-token group
    const int tile = group * 4 + w;             // global 16-token tile
    const int tok0 = tile << 4;

    const float* __restrict__ W = (phase == 0) ? Wq : (phase == 1) ? Wk : Wv;

    // ---- stage W into LDS in fragment layout (coalesced fp32 reads) ----
    {
        const int r = threadIdx.x >> 1;
        const int c0 = (threadIdx.x & 1) * 64;
#pragma unroll
        for (int g = 0; g < 8; g++) {
            const int h = c0 + g * 8;
            bf16x8 v = ld8_f32_bf16(W + r * D + h);
            const int frag = (r >> 4) * 4 + (h >> 5);
            const int ln = ((h & 31) >> 3) * 16 + (r & 15);
            *(bf16x8*)&Wl[(frag * 64 + ln) * 8] = v;
        }
    }

    // x fragments (A layout; identical lane layout serves as B too)
    bf16x8 xa[4];
#pragma unroll
    for (int ks = 0; ks < 4; ks++)
        xa[ks] = ld8_f32_bf16(x + (size_t)(tok0 + l16) * D + ks * 32 + quad * 8);

    __syncthreads();

    bf16* __restrict__ T = Scr[w];

    if (phase < 2) {
        // ---- Q or K: A = x, B = W fragment ----
        bf16* __restrict__ outp = (phase == 0) ? qf : kf;
        const float scale = (phase == 0) ? QSCALE : 1.0f;
#pragma unroll
        for (int nt = 0; nt < 8; nt++) {
            f32x4 acc = {0.f, 0.f, 0.f, 0.f};
#pragma unroll
            for (int ks = 0; ks < 4; ks++) {
                bf16x8 bw = *(const bf16x8*)&Wl[((nt * 4 + ks) * 64 + lane) * 8];
                acc = MFMA16(xa[ks], bw, acc);
            }
            // C: row = token = quad*4+rg, col = n = nt*16+l16
#pragma unroll
            for (int rg = 0; rg < 4; rg++)
                T[(quad * 4 + rg) * 136 + nt * 16 + l16] = (bf16)(acc[rg] * scale);
        }
        // readback fragments (tok = l16), coalesced 1KB stores
#pragma unroll
        for (int ks = 0; ks < 4; ks++) {
            bf16x8 frag = *(const bf16x8*)&T[l16 * 136 + ks * 32 + quad * 8];
            *(bf16x8*)(outp + (((size_t)tile * 4 + ks) * 64 + lane) * 8) = frag;
        }
    } else {
        // ---- V: A = Wv fragment (row = o), B = x (col = token) ----
#pragma unroll
        for (int mt = 0; mt < 8; mt++) {
            f32x4 acc = {0.f, 0.f, 0.f, 0.f};
#pragma unroll
            for (int ks = 0; ks < 4; ks++) {
                bf16x8 aw = *(const bf16x8*)&Wl[((mt * 4 + ks) * 64 + lane) * 8];
                acc = MFMA16(aw, xa[ks], acc);
            }
            // C: row = o = mt*16+quad*4+rg, col = token = l16  ->  T[o][tok]
#pragma unroll
            for (int rg = 0; rg < 4; rg++)
                T[(mt * 16 + quad * 4 + rg) * 20 + l16] = (bf16)acc[rg];
        }
        // This 16-token tile covers kappa in [16*t4, 16*t4+16) of its 64-key
        // group: exactly the jh half (bf16x4) of mfma m for all quads.
        const int g64 = tok0 >> 6;
        const int t4 = (tok0 >> 4) & 3;
        const int m = t4 >> 1;
        const int jh = t4 & 1;
#pragma unroll
        for (int ot = 0; ot < 8; ot++) {
            bf16x4 v4 = *(const bf16x4*)&T[(ot * 16 + l16) * 20 + quad * 4];
            *(bf16x4*)(vf + ((((size_t)g64 * 8 + ot) * 2 + m) * 64 + lane) * 8 +
                       jh * 4) = v4;
        }
    }
}

// ---------------------------------------------------------------------------
// flash: grid 512 x 256 (4 waves). Block = 32 q-rows (2 tiles); wave w =
// key-split w (1024 keys, 16 iters of 64). Swapped QK^T -> P built fully
// in-register (no P LDS, no bank conflicts); V loads hoisted before QK;
// next-iter K prefetched during exp2/PV. fp32 split-combine via LDS.
// ---------------------------------------------------------------------------
__global__ __launch_bounds__(256) __attribute__((amdgpu_waves_per_eu(2, 2)))
void flash(const bf16* __restrict__ qf,
           const bf16* __restrict__ kf,
           const bf16* __restrict__ vf,
           float* __restrict__ out) {
    __shared__ __attribute__((aligned(16))) float Rs[3][2][16 * 148];  // 56832B

    const int lane = threadIdx.x & 63;
    const int w = threadIdx.x >> 6;  // 0..3 = key split
    const int l16 = lane & 15;
    const int quad = lane >> 4;

    // XCD swizzle: bid%8 = XCD; 2 XCDs per batch -> K/V (2MB) L2-resident.
    const int lo = blockIdx.x & 7;
    const int hi = blockIdx.x >> 3;
    const int batch = lo >> 1;
    const int qpair = hi * 2 + (lo & 1);       // 0..127
    const int qtg0 = batch * 256 + qpair * 2;  // global q-tile of tile 0

    bf16x8 aq[2][4];
#pragma unroll
    for (int qt = 0; qt < 2; qt++)
#pragma unroll
        for (int ks = 0; ks < 4; ks++)
            aq[qt][ks] =
                *(const bf16x8*)(qf + (((size_t)(qtg0 + qt) * 4 + ks) * 64 + lane) * 8);

    f32x4 oacc[2][9];
#pragma unroll
    for (int qt = 0; qt < 2; qt++)
#pragma unroll
        for (int i = 0; i < 9; i++) oacc[qt][i] = (f32x4){0.f, 0.f, 0.f, 0.f};

    bf16x8 vone;
#pragma unroll
    for (int j = 0; j < 8; j++) vone[j] = (bf16)1.0f;

    const int kb0 = w * (N / 4);

    // preload K batch for it=0
    bf16x8 bk[4][4];
    {
        const int ktile = batch * 256 + (kb0 >> 4);
#pragma unroll
        for (int nt = 0; nt < 4; nt++)
#pragma unroll
            for (int ks = 0; ks < 4; ks++)
                bk[nt][ks] = *(const bf16x8*)(kf +
                    (((size_t)(ktile + nt) * 4 + ks) * 64 + lane) * 8);
    }
    SB0();

#pragma unroll 1
    for (int it = 0; it < 16; it++) {
        const int kb = kb0 + it * 64;
        const size_t g64v = (size_t)batch * 64 + (kb >> 6);

        // ---- V batch 1 (ot 0..3) issued early: covered by QK + exp2 ----
        bf16x8 bv1[4][2];
#pragma unroll
        for (int ot = 0; ot < 4; ot++)
#pragma unroll
            for (int m = 0; m < 2; m++)
                bv1[ot][m] =
                    *(const bf16x8*)(vf + (((g64v * 8 + ot) * 2 + m) * 64 + lane) * 8);
        SB0();

        // ---- S^T = k.q'' (shared bk across both q-tiles) ----
        f32x4 sv[2][4];
#pragma unroll
        for (int qt = 0; qt < 2; qt++)
#pragma unroll
            for (int nt = 0; nt < 4; nt++) sv[qt][nt] = (f32x4){0.f, 0.f, 0.f, 0.f};
        __builtin_amdgcn_s_setprio(1);
#pragma unroll
        for (int ks = 0; ks < 4; ks++)
#pragma unroll
            for (int nt = 0; nt < 4; nt++) {
                sv[0][nt] = MFMA16(bk[nt][ks], aq[0][ks], sv[0][nt]);
                sv[1][nt] = MFMA16(bk[nt][ks], aq[1][ks], sv[1][nt]);
            }
        __builtin_amdgcn_s_setprio(0);
        SB0();

        // ---- V batch 2 (ot 4..7) ----
        bf16x8 bv2[4][2];
#pragma unroll
        for (int ot = 0; ot < 4; ot++)
#pragma unroll
            for (int m = 0; m < 2; m++)
                bv2[ot][m] = *(const bf16x8*)(vf +
                    (((g64v * 8 + ot + 4) * 2 + m) * 64 + lane) * 8);
        SB0();

        // ---- P = exp2(S^T) -> A-fragments, fully in-register ----
        bf16x8 ap[2][2];
#pragma unroll
        for (int qt = 0; qt < 2; qt++)
#pragma unroll
            for (int m = 0; m < 2; m++) {
                bf16x8 t;
#pragma unroll
                for (int j = 0; j < 4; j++) {
                    t[j] = (bf16)EXP2F(sv[qt][2 * m][j]);
                    t[j + 4] = (bf16)EXP2F(sv[qt][2 * m + 1][j]);
                }
                ap[qt][m] = t;
            }
        SB0();

        // ---- prefetch next iter's K (bk dead after QK) ----
        {
            const int itn = (it < 15) ? it + 1 : 15;
            const int kbn = kb0 + itn * 64;
            const int ktn = batch * 256 + (kbn >> 4);
#pragma unroll
            for (int nt = 0; nt < 4; nt++)
#pragma unroll
                for (int ks = 0; ks < 4; ks++)
                    bk[nt][ks] = *(const bf16x8*)(kf +
                        (((size_t)(ktn + nt) * 4 + ks) * 64 + lane) * 8);
        }
        SB0();

        // ---- O += P.V  (D: row=q=quad*4+rg, col=o=l16) ----
        __builtin_amdgcn_s_setprio(1);
#pragma unroll
        for (int ot = 0; ot < 4; ot++)
#pragma unroll
            for (int m = 0; m < 2; m++) {
                oacc[0][ot] = MFMA16(ap[0][m], bv1[ot][m], oacc[0][ot]);
                oacc[1][ot] = MFMA16(ap[1][m], bv1[ot][m], oacc[1][ot]);
            }
#pragma unroll
        for (int ot = 0; ot < 4; ot++)
#pragma unroll
            for (int m = 0; m < 2; m++) {
                oacc[0][ot + 4] = MFMA16(ap[0][m], bv2[ot][m], oacc[0][ot + 4]);
                oacc[1][ot + 4] = MFMA16(ap[1][m], bv2[ot][m], oacc[1][ot + 4]);
            }
#pragma unroll
        for (int qt = 0; qt < 2; qt++)
#pragma unroll
            for (int m = 0; m < 2; m++)
                oacc[qt][8] = MFMA16(ap[qt][m], vone, oacc[qt][8]);
        __builtin_amdgcn_s_setprio(0);
        SB0();
    }

    // ---- combine the 4 key-split partials through LDS (fp32) ----
    __syncthreads();
    if (w > 0) {
#pragma unroll
        for (int qt = 0; qt < 2; qt++) {
            float* __restrict__ dst = &Rs[w - 1][qt][0];
#pragma unroll
            for (int t = 0; t < 9; t++)
#pragma unroll
                for (int rg = 0; rg < 4; rg++)
                    dst[(quad * 4 + rg) * 148 + t * 16 + l16] = oacc[qt][t][rg];
        }
    }
    __syncthreads();
    if (w == 0) {
#pragma unroll
        for (int qt = 0; qt < 2; qt++) {
#pragma unroll
            for (int sIdx = 0; sIdx < 3; sIdx++) {
                const float* __restrict__ src = &Rs[sIdx][qt][0];
#pragma unroll
                for (int t = 0; t < 9; t++)
#pragma unroll
                    for (int rg = 0; rg < 4; rg++)
                        oacc[qt][t][rg] += src[(quad * 4 + rg) * 148 + t * 16 + l16];
            }
#pragma unroll
            for (int rg = 0; rg < 4; rg++) {
                const float rl = 1.0f / oacc[qt][8][rg];
                float* __restrict__ yrow =
                    out + (((size_t)(qtg0 + qt)) * 16 + quad * 4 + rg) * D;
#pragma unroll
                for (int t = 0; t < 8; t++)
                    yrow[t * 16 + l16] = oacc[qt][t][rg] * rl;
            }
        }
    }
}

// ---------------------------------------------------------------------------
extern "C" void kernel_launch(void* const* d_in, const int* in_sizes, int n_in,
                              void* d_out, int out_size, void* d_ws, size_t ws_size,
                              hipStream_t stream) {
    const float* x = (const float*)d_in[0];
    const float* Wq = (const float*)d_in[1];
    const float* Wk = (const float*)d_in[2];
    const float* Wv = (const float*)d_in[3];
    float* y = (float*)d_out;

    bf16* qf = (bf16*)d_ws;            // 4MB
    bf16* kf = qf + (size_t)ROWS * D;  // 4MB
    bf16* vf = kf + (size_t)ROWS * D;  // 4MB (kappa-permuted fragment layout)

    proj_all<<<768, 256, 0, stream>>>(x, Wq, Wk, Wv, qf, kf, vf);
    flash<<<512, 256, 0, stream>>>(qf, kf, vf, y);
}